// Round 2
// baseline (2266.867 us; speedup 1.0000x reference)
//
#include <hip/hip_runtime.h>
#include <hip/hip_fp16.h>

// MoE top-2: only top-2 experts per token are observable through the gate.
// B=2048, D=1024, O=1024, E=8, H=10240, K_TOP=2.
#define BTOK 2048
#define DIM 1024
#define ODIM 1024
#define NEXP 8
#define HID 10240
#define CAP 2048   // per-expert worst-case token count

typedef _Float16 half8 __attribute__((ext_vector_type(8)));
typedef __fp16 fp16x2 __attribute__((ext_vector_type(2)));  // cvt_pkrtz native type
typedef float floatx4 __attribute__((ext_vector_type(4)));

// ---- workspace layout (bytes) ----
// hidden fp16 [4096][10240] : [0, 83886080)
// counts  int[8]            : 83886080
// offs    int[8]            : 83886112
// tokens  int[8][2048]      : 83886144
// probs   f32[8][2048]      : 83951680
// end: 84017216
#define WS_HIDDEN_OFF 0
#define WS_COUNTS_OFF 83886080UL
#define WS_TOKENS_OFF 83886144UL
#define WS_PROBS_OFF  83951680UL
#define WS_NEEDED     84017216UL

// ---------------- gate: logits -> softmax -> top2 -> expert lists ----------
__global__ void gate_kernel(const float* __restrict__ x1,
                            const float* __restrict__ gate_w,
                            const float* __restrict__ gate_b,
                            int* counts, int* tokens, float* probs) {
    int b = blockIdx.x;
    int lane = threadIdx.x;  // 64 threads = 1 wave
    const float* xr = x1 + (size_t)b * DIM;
    float acc[NEXP];
#pragma unroll
    for (int e = 0; e < NEXP; e++) acc[e] = 0.f;
    for (int i = 0; i < DIM / 64; i++) {
        int d = lane + i * 64;
        float xv = xr[d];
#pragma unroll
        for (int e = 0; e < NEXP; e++) acc[e] += xv * gate_w[e * DIM + d];
    }
#pragma unroll
    for (int e = 0; e < NEXP; e++)
        for (int off = 32; off > 0; off >>= 1) acc[e] += __shfl_xor(acc[e], off);
    if (lane == 0) {
        float l[NEXP], m = -1e30f;
#pragma unroll
        for (int e = 0; e < NEXP; e++) { l[e] = acc[e] + gate_b[e]; m = fmaxf(m, l[e]); }
        float p[NEXP], s = 0.f;
#pragma unroll
        for (int e = 0; e < NEXP; e++) { p[e] = expf(l[e] - m); s += p[e]; }
        float inv = 1.f / s;
        int e0 = 0; float v0 = p[0];
#pragma unroll
        for (int e = 1; e < NEXP; e++) if (p[e] > v0) { v0 = p[e]; e0 = e; }
        int e1 = -1; float v1 = -1.f;
#pragma unroll
        for (int e = 0; e < NEXP; e++) if (e != e0 && p[e] > v1) { v1 = p[e]; e1 = e; }
        int pos0 = atomicAdd(&counts[e0], 1);
        tokens[e0 * CAP + pos0] = b; probs[e0 * CAP + pos0] = v0 * inv;
        int pos1 = atomicAdd(&counts[e1], 1);
        tokens[e1 * CAP + pos1] = b; probs[e1 * CAP + pos1] = v1 * inv;
    }
}

__global__ void offsets_kernel(const int* counts, int* offs) {
    if (threadIdx.x == 0) {
        int r = 0;
        for (int e = 0; e < NEXP; e++) { offs[e] = r; r += counts[e]; }
    }
}

// ---------------- GEMM tiles: 128x128, BK=32, 256 thr (2x2 waves of 64x64) --
#define BM 128
#define BN 128
#define BK 32
#define LDSS 40   // 32 + 8 fp16 pad (keeps rows 16B-aligned, breaks pow2 stride)

__device__ __forceinline__ void cvt_store16(_Float16* dst, float4 a, float4 b,
                                            float4 c, float4 d) {
    union { fp16x2 h2[8]; half8 h8[2]; } u;
    u.h2[0] = __builtin_amdgcn_cvt_pkrtz(a.x, a.y);
    u.h2[1] = __builtin_amdgcn_cvt_pkrtz(a.z, a.w);
    u.h2[2] = __builtin_amdgcn_cvt_pkrtz(b.x, b.y);
    u.h2[3] = __builtin_amdgcn_cvt_pkrtz(b.z, b.w);
    u.h2[4] = __builtin_amdgcn_cvt_pkrtz(c.x, c.y);
    u.h2[5] = __builtin_amdgcn_cvt_pkrtz(c.z, c.w);
    u.h2[6] = __builtin_amdgcn_cvt_pkrtz(d.x, d.y);
    u.h2[7] = __builtin_amdgcn_cvt_pkrtz(d.z, d.w);
    *(half8*)dst = u.h8[0];
    *(half8*)(dst + 8) = u.h8[1];
}

// GEMM1: hidden[off+m, n] = relu( x2[tok(m), :] . fc1_w[e, n, :] + fc1_b[e, n] )
__global__ __launch_bounds__(256, 2) void gemm1_kernel(
    const float* __restrict__ x2, const float* __restrict__ fc1_w,
    const float* __restrict__ fc1_b, const int* __restrict__ counts,
    const int* __restrict__ offs, const int* __restrict__ tokens,
    _Float16* __restrict__ hidden) {
    int e = blockIdx.z;
    int cnt = counts[e];
    int m0 = blockIdx.x * BM;
    if (m0 >= cnt) return;
    int n0 = blockIdx.y * BN;
    int off = offs[e];

    __shared__ _Float16 As[BM][LDSS];
    __shared__ _Float16 Bs[BN][LDSS];

    int t = threadIdx.x, lane = t & 63, wave = t >> 6;
    int waveM = wave & 1, waveN = wave >> 1;
    int srow = t >> 1, shalf = t & 1;          // staging: 16 floats/thread

    int arowc = min(m0 + srow, cnt - 1);
    int tok = tokens[e * CAP + arowc];
    const float* aptr = x2 + (size_t)tok * DIM + shalf * 16;
    const float* bptr = fc1_w + ((size_t)e * HID + n0 + srow) * DIM + shalf * 16;

    floatx4 acc[4][4];
#pragma unroll
    for (int mi = 0; mi < 4; mi++)
#pragma unroll
        for (int ni = 0; ni < 4; ni++) acc[mi][ni] = (floatx4){0.f, 0.f, 0.f, 0.f};

    int fr = lane & 15, quad = lane >> 4;
    for (int kt = 0; kt < DIM / BK; kt++) {
        const float4* ap = (const float4*)(aptr + kt * BK);
        float4 a0 = ap[0], a1 = ap[1], a2 = ap[2], a3 = ap[3];
        const float4* bp = (const float4*)(bptr + kt * BK);
        float4 b0 = bp[0], b1 = bp[1], b2 = bp[2], b3 = bp[3];
        __syncthreads();
        cvt_store16(&As[srow][shalf * 16], a0, a1, a2, a3);
        cvt_store16(&Bs[srow][shalf * 16], b0, b1, b2, b3);
        __syncthreads();
        half8 af[4], bf[4];
#pragma unroll
        for (int mi = 0; mi < 4; mi++)
            af[mi] = *(const half8*)&As[waveM * 64 + mi * 16 + fr][quad * 8];
#pragma unroll
        for (int ni = 0; ni < 4; ni++)
            bf[ni] = *(const half8*)&Bs[waveN * 64 + ni * 16 + fr][quad * 8];
#pragma unroll
        for (int mi = 0; mi < 4; mi++)
#pragma unroll
            for (int ni = 0; ni < 4; ni++)
                acc[mi][ni] = __builtin_amdgcn_mfma_f32_16x16x32_f16(
                    af[mi], bf[ni], acc[mi][ni], 0, 0, 0);
    }
    // epilogue: bias + relu -> fp16 hidden (compact slot layout)
#pragma unroll
    for (int ni = 0; ni < 4; ni++) {
        int col = n0 + waveN * 64 + ni * 16 + fr;
        float bias = fc1_b[e * HID + col];
#pragma unroll
        for (int mi = 0; mi < 4; mi++) {
#pragma unroll
            for (int r = 0; r < 4; r++) {
                int rl = m0 + waveM * 64 + mi * 16 + quad * 4 + r;
                if (rl < cnt) {
                    float v = fmaxf(acc[mi][ni][r] + bias, 0.f);
                    hidden[(size_t)(off + rl) * HID + col] = (_Float16)v;
                }
            }
        }
    }
}

// GEMM2: out[tok(m), n] += p(m) * ( hidden[off+m, :] . fc2_w[e, n, :] + fc2_b[e, n] )
__global__ __launch_bounds__(256, 2) void gemm2_kernel(
    const _Float16* __restrict__ hidden, const float* __restrict__ fc2_w,
    const float* __restrict__ fc2_b, const int* __restrict__ counts,
    const int* __restrict__ offs, const int* __restrict__ tokens,
    const float* __restrict__ probs, float* __restrict__ out) {
    int e = blockIdx.z;
    int cnt = counts[e];
    int m0 = blockIdx.x * BM;
    if (m0 >= cnt) return;
    int n0 = blockIdx.y * BN;
    int off = offs[e];

    __shared__ _Float16 As[BM][LDSS];
    __shared__ _Float16 Bs[BN][LDSS];

    int t = threadIdx.x, lane = t & 63, wave = t >> 6;
    int waveM = wave & 1, waveN = wave >> 1;
    int srow = t >> 1, shalf = t & 1;

    int arowc = min(m0 + srow, cnt - 1);
    const _Float16* aptr = hidden + (size_t)(off + arowc) * HID + shalf * 16;
    const float* bptr = fc2_w + ((size_t)e * ODIM + n0 + srow) * HID + shalf * 16;

    floatx4 acc[4][4];
#pragma unroll
    for (int mi = 0; mi < 4; mi++)
#pragma unroll
        for (int ni = 0; ni < 4; ni++) acc[mi][ni] = (floatx4){0.f, 0.f, 0.f, 0.f};

    int fr = lane & 15, quad = lane >> 4;
    for (int kt = 0; kt < HID / BK; kt++) {
        half8 ha0 = *(const half8*)(aptr + kt * BK);
        half8 ha1 = *(const half8*)(aptr + kt * BK + 8);
        const float4* bp = (const float4*)(bptr + kt * BK);
        float4 b0 = bp[0], b1 = bp[1], b2 = bp[2], b3 = bp[3];
        __syncthreads();
        *(half8*)&As[srow][shalf * 16] = ha0;
        *(half8*)&As[srow][shalf * 16 + 8] = ha1;
        cvt_store16(&Bs[srow][shalf * 16], b0, b1, b2, b3);
        __syncthreads();
        half8 af[4], bf[4];
#pragma unroll
        for (int mi = 0; mi < 4; mi++)
            af[mi] = *(const half8*)&As[waveM * 64 + mi * 16 + fr][quad * 8];
#pragma unroll
        for (int ni = 0; ni < 4; ni++)
            bf[ni] = *(const half8*)&Bs[waveN * 64 + ni * 16 + fr][quad * 8];
#pragma unroll
        for (int mi = 0; mi < 4; mi++)
#pragma unroll
            for (int ni = 0; ni < 4; ni++)
                acc[mi][ni] = __builtin_amdgcn_mfma_f32_16x16x32_f16(
                    af[mi], bf[ni], acc[mi][ni], 0, 0, 0);
    }
    // epilogue: bias, scale by gate prob, atomic-accumulate into out
#pragma unroll
    for (int ni = 0; ni < 4; ni++) {
        int col = n0 + waveN * 64 + ni * 16 + fr;
        float bias = fc2_b[e * ODIM + col];
#pragma unroll
        for (int mi = 0; mi < 4; mi++) {
#pragma unroll
            for (int r = 0; r < 4; r++) {
                int rl = m0 + waveM * 64 + mi * 16 + quad * 4 + r;
                if (rl < cnt) {
                    float p = probs[e * CAP + rl];
                    int tok = tokens[e * CAP + rl];
                    atomicAdd(&out[(size_t)tok * ODIM + col],
                              p * (acc[mi][ni][r] + bias));
                }
            }
        }
    }
}

extern "C" void kernel_launch(void* const* d_in, const int* in_sizes, int n_in,
                              void* d_out, int out_size, void* d_ws, size_t ws_size,
                              hipStream_t stream) {
    if (ws_size < WS_NEEDED) return;  // need 84 MB scratch for compact hidden
    const float* x1 = (const float*)d_in[0];
    const float* x2 = (const float*)d_in[1];
    const float* gate_w = (const float*)d_in[2];
    const float* gate_b = (const float*)d_in[3];
    const float* fc1_w = (const float*)d_in[4];
    const float* fc1_b = (const float*)d_in[5];
    const float* fc2_w = (const float*)d_in[6];
    const float* fc2_b = (const float*)d_in[7];
    float* out = (float*)d_out;
    char* ws = (char*)d_ws;
    _Float16* hidden = (_Float16*)(ws + WS_HIDDEN_OFF);
    int* counts = (int*)(ws + WS_COUNTS_OFF);
    int* offs = counts + NEXP;
    int* tokens = (int*)(ws + WS_TOKENS_OFF);
    float* probs = (float*)(ws + WS_PROBS_OFF);

    (void)hipMemsetAsync(counts, 0, 2 * NEXP * sizeof(int), stream);
    (void)hipMemsetAsync(d_out, 0, (size_t)out_size * sizeof(float), stream);
    gate_kernel<<<BTOK, 64, 0, stream>>>(x1, gate_w, gate_b, counts, tokens, probs);
    offsets_kernel<<<1, 64, 0, stream>>>(counts, offs);
    gemm1_kernel<<<dim3(CAP / BM, HID / BN, NEXP), 256, 0, stream>>>(
        x2, fc1_w, fc1_b, counts, offs, tokens, hidden);
    gemm2_kernel<<<dim3(CAP / BM, ODIM / BN, NEXP), 256, 0, stream>>>(
        hidden, fc2_w, fc2_b, counts, offs, tokens, probs, out);
}

// Round 3
// 1341.498 us; speedup vs baseline: 1.6898x; 1.6898x over previous
//
#include <hip/hip_runtime.h>
#include <hip/hip_fp16.h>

// MoE top-2: only top-2 experts per token are observable through the gate.
// B=2048, D=1024, O=1024, E=8, H=10240, K_TOP=2.
#define BTOK 2048
#define DIM 1024
#define ODIM 1024
#define NEXP 8
#define HID 10240
#define CAP 2048   // per-expert worst-case token count
#define KSPL 4     // split-K factor for gemm2

typedef _Float16 half8 __attribute__((ext_vector_type(8)));
typedef __fp16 fp16x2 __attribute__((ext_vector_type(2)));  // cvt_pkrtz native type
typedef float floatx4 __attribute__((ext_vector_type(4)));

// ---- workspace layout (bytes) ----
#define WS_HIDDEN_OFF 0
#define WS_COUNTS_OFF 83886080UL
#define WS_TOKENS_OFF 83886144UL
#define WS_PROBS_OFF  83951680UL
#define WS_NEEDED     84017216UL

// ---------------- gate: logits -> softmax -> top2 -> expert lists ----------
__global__ void gate_kernel(const float* __restrict__ x1,
                            const float* __restrict__ gate_w,
                            const float* __restrict__ gate_b,
                            int* counts, int* tokens, float* probs) {
    int b = blockIdx.x;
    int lane = threadIdx.x;  // 64 threads = 1 wave
    const float* xr = x1 + (size_t)b * DIM;
    float acc[NEXP];
#pragma unroll
    for (int e = 0; e < NEXP; e++) acc[e] = 0.f;
    for (int i = 0; i < DIM / 64; i++) {
        int d = lane + i * 64;
        float xv = xr[d];
#pragma unroll
        for (int e = 0; e < NEXP; e++) acc[e] += xv * gate_w[e * DIM + d];
    }
#pragma unroll
    for (int e = 0; e < NEXP; e++)
        for (int off = 32; off > 0; off >>= 1) acc[e] += __shfl_xor(acc[e], off);
    if (lane == 0) {
        float l[NEXP], m = -1e30f;
#pragma unroll
        for (int e = 0; e < NEXP; e++) { l[e] = acc[e] + gate_b[e]; m = fmaxf(m, l[e]); }
        float p[NEXP], s = 0.f;
#pragma unroll
        for (int e = 0; e < NEXP; e++) { p[e] = expf(l[e] - m); s += p[e]; }
        float inv = 1.f / s;
        int e0 = 0; float v0 = p[0];
#pragma unroll
        for (int e = 1; e < NEXP; e++) if (p[e] > v0) { v0 = p[e]; e0 = e; }
        int e1 = -1; float v1 = -1.f;
#pragma unroll
        for (int e = 0; e < NEXP; e++) if (e != e0 && p[e] > v1) { v1 = p[e]; e1 = e; }
        int pos0 = atomicAdd(&counts[e0], 1);
        tokens[e0 * CAP + pos0] = b; probs[e0 * CAP + pos0] = v0 * inv;
        int pos1 = atomicAdd(&counts[e1], 1);
        tokens[e1 * CAP + pos1] = b; probs[e1 * CAP + pos1] = v1 * inv;
    }
}

__global__ void offsets_kernel(const int* counts, int* offs) {
    if (threadIdx.x == 0) {
        int r = 0;
        for (int e = 0; e < NEXP; e++) { offs[e] = r; r += counts[e]; }
    }
}

// ---------------- GEMM tiles: 128x128, BK=32, 256 thr (2x2 waves of 64x64) --
#define BM 128
#define BN 128
#define BK 32
#define LDSS 40   // 32 + 8 fp16 pad

__device__ __forceinline__ void cvt_store16(_Float16* dst, float4 a, float4 b,
                                            float4 c, float4 d) {
    union { fp16x2 h2[8]; half8 h8[2]; } u;
    u.h2[0] = __builtin_amdgcn_cvt_pkrtz(a.x, a.y);
    u.h2[1] = __builtin_amdgcn_cvt_pkrtz(a.z, a.w);
    u.h2[2] = __builtin_amdgcn_cvt_pkrtz(b.x, b.y);
    u.h2[3] = __builtin_amdgcn_cvt_pkrtz(b.z, b.w);
    u.h2[4] = __builtin_amdgcn_cvt_pkrtz(c.x, c.y);
    u.h2[5] = __builtin_amdgcn_cvt_pkrtz(c.z, c.w);
    u.h2[6] = __builtin_amdgcn_cvt_pkrtz(d.x, d.y);
    u.h2[7] = __builtin_amdgcn_cvt_pkrtz(d.z, d.w);
    *(half8*)dst = u.h8[0];
    *(half8*)(dst + 8) = u.h8[1];
}

// GEMM1: hidden[off+m, n] = relu( x2[tok(m), :] . fc1_w[e, n, :] + fc1_b[e, n] )
// 1-D grid (10240 blocks), XCD-swizzled: logical = (d%8)*(G/8)+d/8, m fastest.
__global__ __launch_bounds__(256, 2) void gemm1_kernel(
    const float* __restrict__ x2, const float* __restrict__ fc1_w,
    const float* __restrict__ fc1_b, const int* __restrict__ counts,
    const int* __restrict__ offs, const int* __restrict__ tokens,
    _Float16* __restrict__ hidden) {
    int d = blockIdx.x;
    int logical = (d & 7) * (gridDim.x >> 3) + (d >> 3);
    int mt = logical & 15;          // 16 m-tiles (CAP/BM)
    int rest = logical >> 4;
    int nt = rest % (HID / BN);     // 80 n-tiles
    int e = rest / (HID / BN);

    int cnt = counts[e];
    int m0 = mt * BM;
    if (m0 >= cnt) return;
    int n0 = nt * BN;
    int off = offs[e];

    __shared__ _Float16 As[BM][LDSS];
    __shared__ _Float16 Bs[BN][LDSS];

    int t = threadIdx.x, lane = t & 63, wave = t >> 6;
    int waveM = wave & 1, waveN = wave >> 1;
    int srow = t >> 1, shalf = t & 1;          // staging: 16 floats/thread

    int arowc = min(m0 + srow, cnt - 1);
    int tok = tokens[e * CAP + arowc];
    const float* aptr = x2 + (size_t)tok * DIM + shalf * 16;
    const float* bptr = fc1_w + ((size_t)e * HID + n0 + srow) * DIM + shalf * 16;

    floatx4 acc[4][4];
#pragma unroll
    for (int mi = 0; mi < 4; mi++)
#pragma unroll
        for (int ni = 0; ni < 4; ni++) acc[mi][ni] = (floatx4){0.f, 0.f, 0.f, 0.f};

    int fr = lane & 15, quad = lane >> 4;
    // register prefetch pipeline
    float4 a0, a1, a2, a3, b0, b1, b2, b3;
    {
        const float4* ap = (const float4*)aptr;
        a0 = ap[0]; a1 = ap[1]; a2 = ap[2]; a3 = ap[3];
        const float4* bp = (const float4*)bptr;
        b0 = bp[0]; b1 = bp[1]; b2 = bp[2]; b3 = bp[3];
    }
    const int KT = DIM / BK;
    for (int kt = 0; kt < KT; kt++) {
        __syncthreads();
        cvt_store16(&As[srow][shalf * 16], a0, a1, a2, a3);
        cvt_store16(&Bs[srow][shalf * 16], b0, b1, b2, b3);
        __syncthreads();
        if (kt + 1 < KT) {  // prefetch next tile; vmcnt waited at next store
            const float4* ap = (const float4*)(aptr + (kt + 1) * BK);
            a0 = ap[0]; a1 = ap[1]; a2 = ap[2]; a3 = ap[3];
            const float4* bp = (const float4*)(bptr + (kt + 1) * BK);
            b0 = bp[0]; b1 = bp[1]; b2 = bp[2]; b3 = bp[3];
        }
        half8 af[4], bf[4];
#pragma unroll
        for (int mi = 0; mi < 4; mi++)
            af[mi] = *(const half8*)&As[waveM * 64 + mi * 16 + fr][quad * 8];
#pragma unroll
        for (int ni = 0; ni < 4; ni++)
            bf[ni] = *(const half8*)&Bs[waveN * 64 + ni * 16 + fr][quad * 8];
#pragma unroll
        for (int mi = 0; mi < 4; mi++)
#pragma unroll
            for (int ni = 0; ni < 4; ni++)
                acc[mi][ni] = __builtin_amdgcn_mfma_f32_16x16x32_f16(
                    af[mi], bf[ni], acc[mi][ni], 0, 0, 0);
    }
    // epilogue: bias + relu -> fp16 hidden (compact slot layout)
#pragma unroll
    for (int ni = 0; ni < 4; ni++) {
        int col = n0 + waveN * 64 + ni * 16 + fr;
        float bias = fc1_b[e * HID + col];
#pragma unroll
        for (int mi = 0; mi < 4; mi++) {
#pragma unroll
            for (int r = 0; r < 4; r++) {
                int rl = m0 + waveM * 64 + mi * 16 + quad * 4 + r;
                if (rl < cnt) {
                    float v = fmaxf(acc[mi][ni][r] + bias, 0.f);
                    hidden[(size_t)(off + rl) * HID + col] = (_Float16)v;
                }
            }
        }
    }
}

// GEMM2 (split-K x4): out[tok(m), n] += p(m) * (hidden[off+m, ks-chunk] . fc2_w + bias@ks0)
// 1-D grid (4096 blocks), XCD-swizzled, m fastest.
__global__ __launch_bounds__(256, 2) void gemm2_kernel(
    const _Float16* __restrict__ hidden, const float* __restrict__ fc2_w,
    const float* __restrict__ fc2_b, const int* __restrict__ counts,
    const int* __restrict__ offs, const int* __restrict__ tokens,
    const float* __restrict__ probs, float* __restrict__ out) {
    int d = blockIdx.x;
    int logical = (d & 7) * (gridDim.x >> 3) + (d >> 3);
    int mt = logical & 15;          // 16 m-tiles
    int rest = logical >> 4;
    int nt = rest & 7;              // 8 n-tiles (ODIM/BN)
    int rest2 = rest >> 3;
    int ks = rest2 & (KSPL - 1);
    int e = rest2 >> 2;

    int cnt = counts[e];
    int m0 = mt * BM;
    if (m0 >= cnt) return;
    int n0 = nt * BN;
    int off = offs[e];
    int k0 = ks * (HID / KSPL);

    __shared__ _Float16 As[BM][LDSS];
    __shared__ _Float16 Bs[BN][LDSS];

    int t = threadIdx.x, lane = t & 63, wave = t >> 6;
    int waveM = wave & 1, waveN = wave >> 1;
    int srow = t >> 1, shalf = t & 1;

    int arowc = min(m0 + srow, cnt - 1);
    const _Float16* aptr = hidden + (size_t)(off + arowc) * HID + k0 + shalf * 16;
    const float* bptr = fc2_w + ((size_t)e * ODIM + n0 + srow) * HID + k0 + shalf * 16;

    floatx4 acc[4][4];
#pragma unroll
    for (int mi = 0; mi < 4; mi++)
#pragma unroll
        for (int ni = 0; ni < 4; ni++) acc[mi][ni] = (floatx4){0.f, 0.f, 0.f, 0.f};

    int fr = lane & 15, quad = lane >> 4;
    half8 ha0, ha1;
    float4 b0, b1, b2, b3;
    {
        ha0 = *(const half8*)aptr;
        ha1 = *(const half8*)(aptr + 8);
        const float4* bp = (const float4*)bptr;
        b0 = bp[0]; b1 = bp[1]; b2 = bp[2]; b3 = bp[3];
    }
    const int KT = (HID / KSPL) / BK;  // 80
    for (int kt = 0; kt < KT; kt++) {
        __syncthreads();
        *(half8*)&As[srow][shalf * 16] = ha0;
        *(half8*)&As[srow][shalf * 16 + 8] = ha1;
        cvt_store16(&Bs[srow][shalf * 16], b0, b1, b2, b3);
        __syncthreads();
        if (kt + 1 < KT) {
            ha0 = *(const half8*)(aptr + (kt + 1) * BK);
            ha1 = *(const half8*)(aptr + (kt + 1) * BK + 8);
            const float4* bp = (const float4*)(bptr + (kt + 1) * BK);
            b0 = bp[0]; b1 = bp[1]; b2 = bp[2]; b3 = bp[3];
        }
        half8 af[4], bf[4];
#pragma unroll
        for (int mi = 0; mi < 4; mi++)
            af[mi] = *(const half8*)&As[waveM * 64 + mi * 16 + fr][quad * 8];
#pragma unroll
        for (int ni = 0; ni < 4; ni++)
            bf[ni] = *(const half8*)&Bs[waveN * 64 + ni * 16 + fr][quad * 8];
#pragma unroll
        for (int mi = 0; mi < 4; mi++)
#pragma unroll
            for (int ni = 0; ni < 4; ni++)
                acc[mi][ni] = __builtin_amdgcn_mfma_f32_16x16x32_f16(
                    af[mi], bf[ni], acc[mi][ni], 0, 0, 0);
    }
    // epilogue: bias (ks==0 only), scale by gate prob, atomic-accumulate
#pragma unroll
    for (int ni = 0; ni < 4; ni++) {
        int col = n0 + waveN * 64 + ni * 16 + fr;
        float bias = (ks == 0) ? fc2_b[e * ODIM + col] : 0.f;
#pragma unroll
        for (int mi = 0; mi < 4; mi++) {
#pragma unroll
            for (int r = 0; r < 4; r++) {
                int rl = m0 + waveM * 64 + mi * 16 + quad * 4 + r;
                if (rl < cnt) {
                    float p = probs[e * CAP + rl];
                    int tok = tokens[e * CAP + rl];
                    atomicAdd(&out[(size_t)tok * ODIM + col],
                              p * (acc[mi][ni][r] + bias));
                }
            }
        }
    }
}

extern "C" void kernel_launch(void* const* d_in, const int* in_sizes, int n_in,
                              void* d_out, int out_size, void* d_ws, size_t ws_size,
                              hipStream_t stream) {
    if (ws_size < WS_NEEDED) return;  // need 84 MB scratch for compact hidden
    const float* x1 = (const float*)d_in[0];
    const float* x2 = (const float*)d_in[1];
    const float* gate_w = (const float*)d_in[2];
    const float* gate_b = (const float*)d_in[3];
    const float* fc1_w = (const float*)d_in[4];
    const float* fc1_b = (const float*)d_in[5];
    const float* fc2_w = (const float*)d_in[6];
    const float* fc2_b = (const float*)d_in[7];
    float* out = (float*)d_out;
    char* ws = (char*)d_ws;
    _Float16* hidden = (_Float16*)(ws + WS_HIDDEN_OFF);
    int* counts = (int*)(ws + WS_COUNTS_OFF);
    int* offs = counts + NEXP;
    int* tokens = (int*)(ws + WS_TOKENS_OFF);
    float* probs = (float*)(ws + WS_PROBS_OFF);

    (void)hipMemsetAsync(counts, 0, 2 * NEXP * sizeof(int), stream);
    (void)hipMemsetAsync(d_out, 0, (size_t)out_size * sizeof(float), stream);
    gate_kernel<<<BTOK, 64, 0, stream>>>(x1, gate_w, gate_b, counts, tokens, probs);
    offsets_kernel<<<1, 64, 0, stream>>>(counts, offs);
    gemm1_kernel<<<(CAP / BM) * (HID / BN) * NEXP, 256, 0, stream>>>(
        x2, fc1_w, fc1_b, counts, offs, tokens, hidden);
    gemm2_kernel<<<(CAP / BM) * (ODIM / BN) * NEXP * KSPL, 256, 0, stream>>>(
        hidden, fc2_w, fc2_b, counts, offs, tokens, probs, out);
}

// Round 4
// 1268.298 us; speedup vs baseline: 1.7873x; 1.0577x over previous
//
#include <hip/hip_runtime.h>
#include <hip/hip_fp16.h>
#include <stdint.h>

// MoE top-2: B=2048, D=1024, O=1024, E=8, H=10240, top-2 routing.
#define BTOK 2048
#define DIM 1024
#define ODIM 1024
#define NEXP 8
#define HID 10240
#define CAP 2048
#define KSPL 4

typedef _Float16 half8 __attribute__((ext_vector_type(8)));
typedef __fp16 fp16x2 __attribute__((ext_vector_type(2)));
typedef float floatx4 __attribute__((ext_vector_type(4)));

// ---- workspace layout (bytes) ----
#define WS_HIDDEN_OFF 0
#define WS_COUNTS_OFF 83886080UL
#define WS_TOKENS_OFF 83886144UL
#define WS_PROBS_OFF  83951680UL
#define WS_NEEDED     84017216UL

// async global->LDS DMA, 16 B per lane; LDS dest = wave-uniform base + lane*16
typedef __attribute__((address_space(1))) const unsigned int guint;
typedef __attribute__((address_space(3))) unsigned int luint;
__device__ __forceinline__ void gload16(const void* g, void* l) {
    __builtin_amdgcn_global_load_lds((guint*)g, (luint*)l, 16, 0, 0);
}

// ---------------- gate ----------------
__global__ void gate_kernel(const float* __restrict__ x1,
                            const float* __restrict__ gate_w,
                            const float* __restrict__ gate_b,
                            int* counts, int* tokens, float* probs) {
    int b = blockIdx.x;
    int lane = threadIdx.x;
    const float* xr = x1 + (size_t)b * DIM;
    float acc[NEXP];
#pragma unroll
    for (int e = 0; e < NEXP; e++) acc[e] = 0.f;
    for (int i = 0; i < DIM / 64; i++) {
        int d = lane + i * 64;
        float xv = xr[d];
#pragma unroll
        for (int e = 0; e < NEXP; e++) acc[e] += xv * gate_w[e * DIM + d];
    }
#pragma unroll
    for (int e = 0; e < NEXP; e++)
        for (int off = 32; off > 0; off >>= 1) acc[e] += __shfl_xor(acc[e], off);
    if (lane == 0) {
        float l[NEXP], m = -1e30f;
#pragma unroll
        for (int e = 0; e < NEXP; e++) { l[e] = acc[e] + gate_b[e]; m = fmaxf(m, l[e]); }
        float p[NEXP], s = 0.f;
#pragma unroll
        for (int e = 0; e < NEXP; e++) { p[e] = expf(l[e] - m); s += p[e]; }
        float inv = 1.f / s;
        int e0 = 0; float v0 = p[0];
#pragma unroll
        for (int e = 1; e < NEXP; e++) if (p[e] > v0) { v0 = p[e]; e0 = e; }
        int e1 = -1; float v1 = -1.f;
#pragma unroll
        for (int e = 0; e < NEXP; e++) if (e != e0 && p[e] > v1) { v1 = p[e]; e1 = e; }
        int pos0 = atomicAdd(&counts[e0], 1);
        tokens[e0 * CAP + pos0] = b; probs[e0 * CAP + pos0] = v0 * inv;
        int pos1 = atomicAdd(&counts[e1], 1);
        tokens[e1 * CAP + pos1] = b; probs[e1 * CAP + pos1] = v1 * inv;
    }
}

__global__ void offsets_kernel(const int* counts, int* offs) {
    if (threadIdx.x == 0) {
        int r = 0;
        for (int e = 0; e < NEXP; e++) { offs[e] = r; r += counts[e]; }
    }
}

#define BM 128
#define BN 128
#define BK 32

__device__ __forceinline__ half8 cvt8(float4 a, float4 b) {
    union { fp16x2 h2[4]; half8 h8; } u;
    u.h2[0] = __builtin_amdgcn_cvt_pkrtz(a.x, a.y);
    u.h2[1] = __builtin_amdgcn_cvt_pkrtz(a.z, a.w);
    u.h2[2] = __builtin_amdgcn_cvt_pkrtz(b.x, b.y);
    u.h2[3] = __builtin_amdgcn_cvt_pkrtz(b.z, b.w);
    return u.h8;
}

// GEMM1: hidden = relu(x2[tok] . fc1_w^T + b). fp32 tiles DMA'd to LDS (XOR-swizzled).
__global__ __launch_bounds__(256, 3) void gemm1_kernel(
    const float* __restrict__ x2, const float* __restrict__ fc1_w,
    const float* __restrict__ fc1_b, const int* __restrict__ counts,
    const int* __restrict__ offs, const int* __restrict__ tokens,
    _Float16* __restrict__ hidden) {
    int d = blockIdx.x;
    int logical = (d & 7) * (gridDim.x >> 3) + (d >> 3);
    int mt = logical & 15;
    int rest = logical >> 4;
    int nt = rest % (HID / BN);
    int e = rest / (HID / BN);

    int cnt = counts[e];
    int m0 = mt * BM;
    if (m0 >= cnt) return;
    int n0 = nt * BN;
    int off = offs[e];

    // fp32 tiles, rows of 32 floats (128 B), 16B groups swizzled by g^(row&7)
    __shared__ __align__(16) float As[BM * BK];
    __shared__ __align__(16) float Bs[BN * BK];

    int t = threadIdx.x, lane = t & 63, wave = t >> 6;
    int waveM = wave & 1, waveN = wave >> 1;

    // staging addresses: chunk i covers slots s=i*256+t; row=(s>>3)=i*32+(t>>3),
    // g=(t&7)^(row&7) (same for all i since 32i%8==0)
    int srow = t >> 3;
    int sg = (t & 7) ^ (srow & 7);
    const char* abase[4];
#pragma unroll
    for (int i = 0; i < 4; i++) {
        int row = i * 32 + srow;
        int arow = min(m0 + row, cnt - 1);
        int tok = tokens[e * CAP + arow];
        abase[i] = (const char*)(x2 + (size_t)tok * DIM + sg * 4);
    }
    const char* bbase = (const char*)(fc1_w + ((size_t)e * HID + n0 + srow) * DIM + sg * 4);
    char* asd = (char*)As + wave * 1024;
    char* bsd = (char*)Bs + wave * 1024;

    floatx4 acc[4][4];
#pragma unroll
    for (int mi = 0; mi < 4; mi++)
#pragma unroll
        for (int ni = 0; ni < 4; ni++) acc[mi][ni] = (floatx4){0.f, 0.f, 0.f, 0.f};

    int fr = lane & 15, q = lane >> 4;
    // prologue: tile 0
#pragma unroll
    for (int i = 0; i < 4; i++) {
        gload16(abase[i], asd + i * 4096);
        gload16(bbase + i * (32 * DIM * 4), bsd + i * 4096);
    }
    const int KT = DIM / BK;
    for (int kt = 0; kt < KT; kt++) {
        __syncthreads();  // drains vmcnt -> tile kt resident in LDS
        half8 af[4], bf[4];
#pragma unroll
        for (int mi = 0; mi < 4; mi++) {
            int row = waveM * 64 + mi * 16 + fr;
            float4 f0 = *(const float4*)((const char*)As + row * 128 + ((2 * q) ^ (row & 7)) * 16);
            float4 f1 = *(const float4*)((const char*)As + row * 128 + ((2 * q + 1) ^ (row & 7)) * 16);
            af[mi] = cvt8(f0, f1);
        }
#pragma unroll
        for (int ni = 0; ni < 4; ni++) {
            int row = waveN * 64 + ni * 16 + fr;
            float4 f0 = *(const float4*)((const char*)Bs + row * 128 + ((2 * q) ^ (row & 7)) * 16);
            float4 f1 = *(const float4*)((const char*)Bs + row * 128 + ((2 * q + 1) ^ (row & 7)) * 16);
            bf[ni] = cvt8(f0, f1);
        }
        __syncthreads();  // all waves done reading LDS (nothing outstanding: cheap)
        if (kt + 1 < KT) {  // DMA next tile; latency overlaps the MFMA block below
            int koff = (kt + 1) * 128;
#pragma unroll
            for (int i = 0; i < 4; i++) {
                gload16(abase[i] + koff, asd + i * 4096);
                gload16(bbase + i * (32 * DIM * 4) + koff, bsd + i * 4096);
            }
        }
#pragma unroll
        for (int mi = 0; mi < 4; mi++)
#pragma unroll
            for (int ni = 0; ni < 4; ni++)
                acc[mi][ni] = __builtin_amdgcn_mfma_f32_16x16x32_f16(
                    af[mi], bf[ni], acc[mi][ni], 0, 0, 0);
    }
    // epilogue: bias + relu -> fp16 hidden (compact slots)
#pragma unroll
    for (int ni = 0; ni < 4; ni++) {
        int col = n0 + waveN * 64 + ni * 16 + fr;
        float bias = fc1_b[e * HID + col];
#pragma unroll
        for (int mi = 0; mi < 4; mi++) {
#pragma unroll
            for (int r = 0; r < 4; r++) {
                int rl = m0 + waveM * 64 + mi * 16 + q * 4 + r;
                if (rl < cnt) {
                    float v = fmaxf(acc[mi][ni][r] + bias, 0.f);
                    hidden[(size_t)(off + rl) * HID + col] = (_Float16)v;
                }
            }
        }
    }
}

// GEMM2 (split-K x4): A = hidden fp16 (DMA, swizzle g^((row>>1)&3)), B = fc2_w fp32.
__global__ __launch_bounds__(256, 3) void gemm2_kernel(
    const _Float16* __restrict__ hidden, const float* __restrict__ fc2_w,
    const float* __restrict__ fc2_b, const int* __restrict__ counts,
    const int* __restrict__ offs, const int* __restrict__ tokens,
    const float* __restrict__ probs, float* __restrict__ out) {
    int d = blockIdx.x;
    int logical = (d & 7) * (gridDim.x >> 3) + (d >> 3);
    int mt = logical & 15;
    int rest = logical >> 4;
    int nt = rest & 7;
    int rest2 = rest >> 3;
    int ks = rest2 & (KSPL - 1);
    int e = rest2 >> 2;

    int cnt = counts[e];
    int m0 = mt * BM;
    if (m0 >= cnt) return;
    int n0 = nt * BN;
    int off = offs[e];
    int k0 = ks * (HID / KSPL);

    __shared__ __align__(16) _Float16 Ash[BM * BK];  // rows of 32 fp16 (64 B)
    __shared__ __align__(16) float Bs[BN * BK];      // rows of 32 fp32 (128 B)

    int t = threadIdx.x, lane = t & 63, wave = t >> 6;
    int waveM = wave & 1, waveN = wave >> 1;

    // A staging: 2 chunks; slot s=i*256+t; row=i*64+(t>>2); g=(t&3)^((row>>1)&3)
    int sarow = t >> 2;
    int sag = (t & 3) ^ ((sarow >> 1) & 3);
    const char* abase[2];
#pragma unroll
    for (int i = 0; i < 2; i++) {
        int row = i * 64 + sarow;
        int arow = min(m0 + row, cnt - 1);
        abase[i] = (const char*)(hidden + (size_t)(off + arow) * HID + k0 + sag * 8);
    }
    // B staging: 4 chunks; row=i*32+(t>>3); g=(t&7)^(row&7)
    int sbrow = t >> 3;
    int sbg = (t & 7) ^ (sbrow & 7);
    const char* bbase = (const char*)(fc2_w + ((size_t)e * ODIM + n0 + sbrow) * HID + k0 + sbg * 4);
    char* asd = (char*)Ash + wave * 1024;
    char* bsd = (char*)Bs + wave * 1024;

    floatx4 acc[4][4];
#pragma unroll
    for (int mi = 0; mi < 4; mi++)
#pragma unroll
        for (int ni = 0; ni < 4; ni++) acc[mi][ni] = (floatx4){0.f, 0.f, 0.f, 0.f};

    int fr = lane & 15, q = lane >> 4;
#pragma unroll
    for (int i = 0; i < 2; i++) gload16(abase[i], asd + i * 4096);
#pragma unroll
    for (int i = 0; i < 4; i++) gload16(bbase + i * (32 * HID * 4), bsd + i * 4096);

    const int KT = (HID / KSPL) / BK;  // 80
    for (int kt = 0; kt < KT; kt++) {
        __syncthreads();
        half8 af[4], bf[4];
#pragma unroll
        for (int mi = 0; mi < 4; mi++) {
            int row = waveM * 64 + mi * 16 + fr;
            af[mi] = *(const half8*)((const char*)Ash + row * 64 + (q ^ ((row >> 1) & 3)) * 16);
        }
#pragma unroll
        for (int ni = 0; ni < 4; ni++) {
            int row = waveN * 64 + ni * 16 + fr;
            float4 f0 = *(const float4*)((const char*)Bs + row * 128 + ((2 * q) ^ (row & 7)) * 16);
            float4 f1 = *(const float4*)((const char*)Bs + row * 128 + ((2 * q + 1) ^ (row & 7)) * 16);
            bf[ni] = cvt8(f0, f1);
        }
        __syncthreads();
        if (kt + 1 < KT) {
            int koffA = (kt + 1) * 64;   // 32 fp16
            int koffB = (kt + 1) * 128;  // 32 fp32
#pragma unroll
            for (int i = 0; i < 2; i++) gload16(abase[i] + koffA, asd + i * 4096);
#pragma unroll
            for (int i = 0; i < 4; i++) gload16(bbase + i * (32 * HID * 4) + koffB, bsd + i * 4096);
        }
#pragma unroll
        for (int mi = 0; mi < 4; mi++)
#pragma unroll
            for (int ni = 0; ni < 4; ni++)
                acc[mi][ni] = __builtin_amdgcn_mfma_f32_16x16x32_f16(
                    af[mi], bf[ni], acc[mi][ni], 0, 0, 0);
    }
#pragma unroll
    for (int ni = 0; ni < 4; ni++) {
        int col = n0 + waveN * 64 + ni * 16 + fr;
        float bias = (ks == 0) ? fc2_b[e * ODIM + col] : 0.f;
#pragma unroll
        for (int mi = 0; mi < 4; mi++) {
#pragma unroll
            for (int r = 0; r < 4; r++) {
                int rl = m0 + waveM * 64 + mi * 16 + q * 4 + r;
                if (rl < cnt) {
                    float p = probs[e * CAP + rl];
                    int tok = tokens[e * CAP + rl];
                    atomicAdd(&out[(size_t)tok * ODIM + col],
                              p * (acc[mi][ni][r] + bias));
                }
            }
        }
    }
}

extern "C" void kernel_launch(void* const* d_in, const int* in_sizes, int n_in,
                              void* d_out, int out_size, void* d_ws, size_t ws_size,
                              hipStream_t stream) {
    if (ws_size < WS_NEEDED) return;
    const float* x1 = (const float*)d_in[0];
    const float* x2 = (const float*)d_in[1];
    const float* gate_w = (const float*)d_in[2];
    const float* gate_b = (const float*)d_in[3];
    const float* fc1_w = (const float*)d_in[4];
    const float* fc1_b = (const float*)d_in[5];
    const float* fc2_w = (const float*)d_in[6];
    const float* fc2_b = (const float*)d_in[7];
    float* out = (float*)d_out;
    char* ws = (char*)d_ws;
    _Float16* hidden = (_Float16*)(ws + WS_HIDDEN_OFF);
    int* counts = (int*)(ws + WS_COUNTS_OFF);
    int* offs = counts + NEXP;
    int* tokens = (int*)(ws + WS_TOKENS_OFF);
    float* probs = (float*)(ws + WS_PROBS_OFF);

    (void)hipMemsetAsync(counts, 0, 2 * NEXP * sizeof(int), stream);
    (void)hipMemsetAsync(d_out, 0, (size_t)out_size * sizeof(float), stream);
    gate_kernel<<<BTOK, 64, 0, stream>>>(x1, gate_w, gate_b, counts, tokens, probs);
    offsets_kernel<<<1, 64, 0, stream>>>(counts, offs);
    gemm1_kernel<<<(CAP / BM) * (HID / BN) * NEXP, 256, 0, stream>>>(
        x2, fc1_w, fc1_b, counts, offs, tokens, hidden);
    gemm2_kernel<<<(CAP / BM) * (ODIM / BN) * NEXP * KSPL, 256, 0, stream>>>(
        hidden, fc2_w, fc2_b, counts, offs, tokens, probs, out);
}